// Round 12
// baseline (131.712 us; speedup 1.0000x reference)
//
#include <hip/hip_runtime.h>

#define BB 2
#define CIN 64
#define CQ 32
#define DD 8
#define HH 16
#define WWW 16
#define NN 2048   // D*H*W
#define NHW 256   // H*W
#define COUT 64

#define XPLANE 324          // 18*18 padded plane (conv_out)
#define CI_OUT 8            // ci per block (out conv) -- single stage

// conv_qkv spatial-quad geometry
#define QROWS 18
#define QCOLS 20
#define QPLANE (QROWS * QCOLS)   // 360 floats
#define QCI 4               // ci per staging phase

#define LOG2E 1.44269504088896340736f

__device__ __forceinline__ float fast_exp2(float x) {
#if __has_builtin(__builtin_amdgcn_exp2f)
    return __builtin_amdgcn_exp2f(x);    // single v_exp_f32
#else
    return exp2f(x);
#endif
}

// ---- init: qkv <- bias ; out <- x + bias ; zbuf,ybuf <- 0 ----
__global__ __launch_bounds__(256) void init_kernel(
    const float* __restrict__ bk, const float* __restrict__ bq, const float* __restrict__ bv,
    const float* __restrict__ ba, const float* __restrict__ x,
    float* __restrict__ kout, float* __restrict__ qout, float* __restrict__ vout,
    float* __restrict__ out, float* __restrict__ zbuf, float* __restrict__ ybuf)
{
    int i = blockIdx.x * 256 + threadIdx.x;
    if (i < BB * CQ * NN) {
        int co = (i >> 11) & 31;
        kout[i] = bk[co];
        qout[i] = bq[co];
        vout[i] = bv[co];
    } else if (i < 3 * BB * CQ * NN) {
        int j = i - BB * CQ * NN;             // 0 .. 262143
        int co = (j >> 11) & 63;
        out[j] = x[j] + ba[co];
    } else if (i < 3 * BB * CQ * NN + CQ * NN) {
        zbuf[i - 3 * BB * CQ * NN] = 0.f;
    } else {
        ybuf[i - 3 * BB * CQ * NN - CQ * NN] = 0.f;
    }
}

// ---- fused k,q,v conv: grid 1024 = 8cisplit(HIGH) x {2b,2dq,32co}(LOW) ----
// r11 post-mortem: per-ci weight s_loads share lgkmcnt with ds_reads, and SMEM
// returns out-of-order -> each weight use forces lgkmcnt(0), draining the DS
// queue 3x/ci. Stall is per-wave serial -> occupancy-insensitive (26% VALUBusy
// at both 2 and 4 waves/SIMD). Fix: preload the block's 648 weight floats into
// LDS once (wlds, 2.6 KB); weight reads become wave-uniform broadcast ds_read
// (IN-ORDER -> compiler uses partial lgkmcnt(N), no drains). w-quad keeps
// 324 FMA per ~39 ds-ops per ci -> VALU-bound.
__global__ __launch_bounds__(256, 4) void conv_qkv_kernel(
    const float* __restrict__ x,
    const float* __restrict__ wk, const float* __restrict__ wq, const float* __restrict__ wv,
    float* __restrict__ kout, float* __restrict__ qout, float* __restrict__ vout)
{
    int bid   = blockIdx.x;
    int split = bid >> 7;          // 0..7 HIGH bits -> partners same bid%8 -> same XCD
    int inner = bid & 127;
    int co    = inner & 31;
    int dq    = (inner >> 5) & 1;
    int b     = inner >> 6;
    int ci0   = split << 3;        // 8 ci per split
    int d0    = dq << 2;           // output planes d0 .. d0+3

    __shared__ float smem[QCI * 6 * QPLANE];   // 34560 B; epilogue reuses first 12 KB
    __shared__ float wlds[3 * 8 * 27];         // 2592 B: [set][ci_loc][27]
    float* xl = smem;
    float* tl = smem;              // alias: xl dead before tl writes (barrier-separated)

    int tid = threadIdx.x;
    int hw = tid >> 4;
    int ww = tid & 15;
    int wr = (hw + 1) * QCOLS + (ww + 1);
    int pn  = tid >> 6;            // 0..3 d-plane (wave id)
    int rem = tid & 63;
    int h   = rem & 15;            // 0..15  (bank-conflict-free read map)
    int wqi = rem >> 4;            // 0..3

    const float* xb = x + ((size_t)b * CIN + ci0) * NN;

    // ---- one-time weight preload: 648 floats, coalesced ----
    {
        size_t wbase = ((size_t)co * CIN + ci0) * 27;
        for (int i = tid; i < 648; i += 256) {
            const float* src = (i < 216) ? (wk + wbase + i)
                             : (i < 432) ? (wq + wbase + (i - 216))
                                         : (wv + wbase + (i - 432));
            wlds[i] = *src;
        }
    }

    float r[QCI * 6];
    #pragma unroll
    for (int p = 0; p < 6; ++p) {
        int dd = d0 - 1 + p;
        if (dd >= 0 && dd < DD) {              // block-uniform
            #pragma unroll
            for (int cl = 0; cl < QCI; ++cl)
                r[cl * 6 + p] = xb[(size_t)cl * NN + dd * NHW + tid];
        }
    }
    for (int i = tid; i < QCI * 6 * QPLANE; i += 256) xl[i] = 0.f;
    __syncthreads();
    #pragma unroll
    for (int p = 0; p < 6; ++p) {
        int dd = d0 - 1 + p;
        if (dd >= 0 && dd < DD) {
            #pragma unroll
            for (int cl = 0; cl < QCI; ++cl)
                xl[cl * 6 * QPLANE + p * QPLANE + wr] = r[cl * 6 + p];
        }
    }

    float acc[3][4];
    #pragma unroll
    for (int s = 0; s < 3; ++s)
        #pragma unroll
        for (int o = 0; o < 4; ++o) acc[s][o] = 0.f;

    #pragma unroll 1
    for (int ph = 0; ph < 2; ++ph) {
        __syncthreads();
        if (ph == 0) {
            #pragma unroll
            for (int p = 0; p < 6; ++p) {
                int dd = d0 - 1 + p;
                if (dd >= 0 && dd < DD) {
                    #pragma unroll
                    for (int cl = 0; cl < QCI; ++cl)
                        r[cl * 6 + p] = xb[(size_t)(QCI + cl) * NN + dd * NHW + tid];
                }
            }
        }

        for (int cl = 0; cl < QCI; ++cl) {
            int cil = ph * QCI + cl;
            const float* wl0 = wlds + (0 * 8 + cil) * 27;   // k weights, this ci
            const float* wl1 = wlds + (1 * 8 + cil) * 27;   // q
            const float* wl2 = wlds + (2 * 8 + cil) * 27;   // v
            const float* xp  = xl + cl * 6 * QPLANE + pn * QPLANE + h * QCOLS + wqi * 4;

            #pragma unroll
            for (int kd = 0; kd < 3; ++kd) {
                // per-kd weight rows from LDS (broadcast ds_read, in-order pipe)
                float w0r[9], w1r[9], w2r[9];
                #pragma unroll
                for (int j = 0; j < 9; ++j) {
                    int t = kd * 9 + j;
                    w0r[j] = wl0[t]; w1r[j] = wl1[t]; w2r[j] = wl2[t];
                }
                #pragma unroll
                for (int kh = 0; kh < 3; ++kh) {
                    const float* xr = xp + kd * QPLANE + kh * QCOLS;
                    float4 xa  = *(const float4*)xr;
                    float2 xb2 = *(const float2*)(xr + 4);
                    float xw[6] = {xa.x, xa.y, xa.z, xa.w, xb2.x, xb2.y};
                    #pragma unroll
                    for (int kw = 0; kw < 3; ++kw) {
                        int t = kh * 3 + kw;
                        #pragma unroll
                        for (int o = 0; o < 4; ++o) {
                            float xv = xw[o + kw];
                            acc[0][o] = fmaf(w0r[t], xv, acc[0][o]);
                            acc[1][o] = fmaf(w1r[t], xv, acc[1][o]);
                            acc[2][o] = fmaf(w2r[t], xv, acc[2][o]);
                        }
                    }
                }
            }
        }

        __syncthreads();
        if (ph == 0) {
            #pragma unroll
            for (int p = 0; p < 6; ++p) {
                int dd = d0 - 1 + p;
                if (dd >= 0 && dd < DD) {
                    #pragma unroll
                    for (int cl = 0; cl < QCI; ++cl)
                        xl[cl * 6 * QPLANE + p * QPLANE + wr] = r[cl * 6 + p];
                }
            }
        }
    }

    // ---- epilogue: LDS transpose (aliased into xl) -> contiguous atomic lanes ----
    size_t base = ((size_t)b * CQ + co) * NN + d0 * NHW;
    int wloc = pn * 256 + h * 16 + wqi * 4;
    __syncthreads();   // all xl reads complete before tl overwrite
    {
        float4 f0; f0.x = acc[0][0]; f0.y = acc[0][1]; f0.z = acc[0][2]; f0.w = acc[0][3];
        float4 f1; f1.x = acc[1][0]; f1.y = acc[1][1]; f1.z = acc[1][2]; f1.w = acc[1][3];
        float4 f2; f2.x = acc[2][0]; f2.y = acc[2][1]; f2.z = acc[2][2]; f2.w = acc[2][3];
        *(float4*)&tl[wloc]        = f0;
        *(float4*)&tl[1024 + wloc] = f1;
        *(float4*)&tl[2048 + wloc] = f2;
    }
    __syncthreads();
    #pragma unroll
    for (int p = 0; p < 4; ++p) {
        unsafeAtomicAdd(&kout[base + p * NHW + tid], tl[p * 256 + tid]);
        unsafeAtomicAdd(&qout[base + p * NHW + tid], tl[1024 + p * 256 + tid]);
        unsafeAtomicAdd(&vout[base + p * NHW + tid], tl[2048 + p * 256 + tid]);
    }
}

// ---- per-(b,c) row max|q|: grid 64 x 256 ----
__global__ __launch_bounds__(256) void qmax_kernel(
    const float* __restrict__ qbuf, float* __restrict__ mq)
{
    int row = blockIdx.x;
    int tid = threadIdx.x;
    const float4* q = (const float4*)(qbuf + (size_t)row * NN);
    float4 v0 = q[tid], v1 = q[tid + 256];
    float mx = fmaxf(fmaxf(fmaxf(fabsf(v0.x), fabsf(v0.y)), fmaxf(fabsf(v0.z), fabsf(v0.w))),
                     fmaxf(fmaxf(fabsf(v1.x), fabsf(v1.y)), fmaxf(fabsf(v1.z), fabsf(v1.w))));
    #pragma unroll
    for (int off = 32; off; off >>= 1)
        mx = fmaxf(mx, __shfl_down(mx, off, 64));
    __shared__ float red[4];
    if ((tid & 63) == 0) red[tid >> 6] = mx;
    __syncthreads();
    if (tid == 0) mq[row] = fmaxf(fmaxf(red[0], red[1]), fmaxf(red[2], red[3]));
}

// ---- softmax denominators with upper-bound shift: grid 1024 ----
__global__ __launch_bounds__(256) void mz_partial_kernel(
    const float* __restrict__ kbuf, const float* __restrict__ qbuf,
    const float* __restrict__ mq, float* __restrict__ zbuf)
{
    int bid = blockIdx.x;
    int nchunk = bid >> 7;
    int c      = (bid >> 2) & 31;
    int mtile  = bid & 3;

    __shared__ float q0l[256], q1l[256];
    int tid = threadIdx.x;
    int n0 = nchunk * 256;
    if (tid < 64) {
        float4 v = ((const float4*)(qbuf + (size_t)c * NN + n0))[tid];
        v.x *= LOG2E; v.y *= LOG2E; v.z *= LOG2E; v.w *= LOG2E;
        ((float4*)q0l)[tid] = v;
    } else if (tid < 128) {
        float4 v = ((const float4*)(qbuf + (size_t)(CQ + c) * NN + n0))[tid - 64];
        v.x *= LOG2E; v.y *= LOG2E; v.z *= LOG2E; v.w *= LOG2E;
        ((float4*)q1l)[tid - 64] = v;
    }
    __syncthreads();

    int m = mtile * 512 + tid * 2;
    float2 k0 = *(const float2*)(kbuf + (size_t)c * NN + m);
    float2 k1 = *(const float2*)(kbuf + (size_t)(CQ + c) * NN + m);
    float mq0 = mq[c], mq1 = mq[CQ + c];

    float nma = -LOG2E * fmaf(fabsf(k0.x), mq0, fabsf(k1.x) * mq1);
    float nmb = -LOG2E * fmaf(fabsf(k0.y), mq0, fabsf(k1.y) * mq1);

    const float4* q0v = (const float4*)q0l;
    const float4* q1v = (const float4*)q1l;

    float za = 0.f, zb = 0.f;
    #pragma unroll 4
    for (int i = 0; i < 64; ++i) {
        float4 a = q0v[i], b4 = q1v[i];
        za += fast_exp2(fmaf(k0.x, a.x, fmaf(k1.x, b4.x, nma)))
            + fast_exp2(fmaf(k0.x, a.y, fmaf(k1.x, b4.y, nma)))
            + fast_exp2(fmaf(k0.x, a.z, fmaf(k1.x, b4.z, nma)))
            + fast_exp2(fmaf(k0.x, a.w, fmaf(k1.x, b4.w, nma)));
        zb += fast_exp2(fmaf(k0.y, a.x, fmaf(k1.y, b4.x, nmb)))
            + fast_exp2(fmaf(k0.y, a.y, fmaf(k1.y, b4.y, nmb)))
            + fast_exp2(fmaf(k0.y, a.z, fmaf(k1.y, b4.z, nmb)))
            + fast_exp2(fmaf(k0.y, a.w, fmaf(k1.y, b4.w, nmb)));
    }
    unsafeAtomicAdd(&zbuf[(size_t)c * NN + m],     za);
    unsafeAtomicAdd(&zbuf[(size_t)c * NN + m + 1], zb);
}

// ---- attention apply, accumulating directly into ybuf: grid 1024 ----
__global__ __launch_bounds__(256) void att_partial_kernel(
    const float* __restrict__ kbuf, const float* __restrict__ qbuf,
    const float* __restrict__ vbuf,
    const float* __restrict__ mq, const float* __restrict__ zbuf,
    float* __restrict__ ybuf)
{
    int bid = blockIdx.x;
    int mchunk = bid >> 7;
    int c      = (bid >> 2) & 31;
    int ntile  = bid & 3;

    __shared__ float k0l[256], k1l[256], vz0l[256], vz1l[256], nMl[256];
    int tid = threadIdx.x;
    {
        int m = mchunk * 256 + tid;
        float k0 = kbuf[(size_t)c * NN + m];
        float k1 = kbuf[(size_t)(CQ + c) * NN + m];
        float mq0 = mq[c], mq1 = mq[CQ + c];
        float rz = 1.f / zbuf[(size_t)c * NN + m];
        k0l[tid]  = k0;
        k1l[tid]  = k1;
        vz0l[tid] = vbuf[(size_t)c * NN + m] * rz;
        vz1l[tid] = vbuf[(size_t)(CQ + c) * NN + m] * rz;
        nMl[tid]  = -LOG2E * fmaf(fabsf(k0), mq0, fabsf(k1) * mq1);
    }
    __syncthreads();

    int n = ntile * 512 + tid * 2;
    float2 q0 = *(const float2*)(qbuf + (size_t)c * NN + n);
    float2 q1 = *(const float2*)(qbuf + (size_t)(CQ + c) * NN + n);
    q0.x *= LOG2E; q0.y *= LOG2E;
    q1.x *= LOG2E; q1.y *= LOG2E;

    const float4* k0v = (const float4*)k0l;
    const float4* k1v = (const float4*)k1l;
    const float4* v0v = (const float4*)vz0l;
    const float4* v1v = (const float4*)vz1l;
    const float4* nMv = (const float4*)nMl;

    float a00 = 0.f, a01 = 0.f;   // b=0: n, n+1
    float a10 = 0.f, a11 = 0.f;   // b=1

    #pragma unroll 2
    for (int i = 0; i < 64; ++i) {
        float4 kk0 = k0v[i], kk1 = k1v[i], w0 = v0v[i], w1 = v1v[i], nm = nMv[i];
        #define ATTS(KX,K1X,W0X,W1X,NMX) { \
            float e0 = fast_exp2(fmaf(q0.x, KX, fmaf(q1.x, K1X, NMX))); \
            float e1 = fast_exp2(fmaf(q0.y, KX, fmaf(q1.y, K1X, NMX))); \
            a00 = fmaf(e0, W0X, a00); a10 = fmaf(e0, W1X, a10); \
            a01 = fmaf(e1, W0X, a01); a11 = fmaf(e1, W1X, a11); }
        ATTS(kk0.x, kk1.x, w0.x, w1.x, nm.x)
        ATTS(kk0.y, kk1.y, w0.y, w1.y, nm.y)
        ATTS(kk0.z, kk1.z, w0.z, w1.z, nm.z)
        ATTS(kk0.w, kk1.w, w0.w, w1.w, nm.w)
        #undef ATTS
    }

    size_t base = ((size_t)c * NN + n) * BB;   // ybuf flat [c][n][b]
    unsafeAtomicAdd(&ybuf[base + 0], a00);
    unsafeAtomicAdd(&ybuf[base + 1], a10);
    unsafeAtomicAdd(&ybuf[base + 2], a01);
    unsafeAtomicAdd(&ybuf[base + 3], a11);
}

// ---- final conv (32->64): grid 2b*8d*16cog*4cisplit = 1024 blocks ----
__global__ __launch_bounds__(256, 4) void conv_out_kernel(
    const float* __restrict__ ybuf,
    const float* __restrict__ wa,
    float* __restrict__ out)
{
    int bid   = blockIdx.x;
    int split = bid & 3;
    int cog   = (bid >> 2) & 15;
    int d     = (bid >> 6) & 7;
    int b     = bid >> 9;
    int co0   = cog << 2;
    int ci0   = split << 3;   // 8 ci per split

    __shared__ float yl[CI_OUT * 3 * XPLANE];   // 31104 B

    int tid = threadIdx.x;
    int h  = tid >> 4;
    int w  = tid & 15;
    int wr = (h + 1) * 18 + (w + 1);
    int rb = h * 18 + w;

    const float* yb = ybuf + ((size_t)b * CQ + ci0) * NN;   // [C,N,B] flat as [B][32][2048]

    float r[CI_OUT * 3];
    #pragma unroll
    for (int kd = 0; kd < 3; ++kd) {
        int dd = d + kd - 1;
        bool ok = (dd >= 0) && (dd < DD);
        #pragma unroll
        for (int cc = 0; cc < CI_OUT; ++cc)
            r[cc * 3 + kd] = ok ? yb[(size_t)cc * NN + dd * NHW + tid] : 0.f;
    }
    for (int i = tid; i < CI_OUT * 3 * XPLANE; i += 256) yl[i] = 0.f;
    __syncthreads();
    #pragma unroll
    for (int j = 0; j < CI_OUT * 3; ++j)
        yl[j * XPLANE + wr] = r[j];
    __syncthreads();

    float a0 = 0.f, a1 = 0.f, a2 = 0.f, a3 = 0.f;

    for (int cc = 0; cc < CI_OUT; ++cc) {
        int ci = ci0 + cc;
        const float* w0 = wa + ((size_t)(co0 + 0) * CQ + ci) * 27;
        const float* w1 = wa + ((size_t)(co0 + 1) * CQ + ci) * 27;
        const float* w2 = wa + ((size_t)(co0 + 2) * CQ + ci) * 27;
        const float* w3 = wa + ((size_t)(co0 + 3) * CQ + ci) * 27;
        const float* yp = yl + cc * 3 * XPLANE + rb;
        #pragma unroll
        for (int kd = 0; kd < 3; ++kd) {
            int dd = d + kd - 1;
            if (dd < 0 || dd >= DD) continue;   // block-uniform
            #pragma unroll
            for (int kh = 0; kh < 3; ++kh) {
                #pragma unroll
                for (int kw = 0; kw < 3; ++kw) {
                    float yv = yp[kd * XPLANE + kh * 18 + kw];
                    int t = kd * 9 + kh * 3 + kw;
                    a0 = fmaf(yv, w0[t], a0);
                    a1 = fmaf(yv, w1[t], a1);
                    a2 = fmaf(yv, w2[t], a2);
                    a3 = fmaf(yv, w3[t], a3);
                }
            }
        }
    }

    size_t o = ((size_t)b * COUT + co0) * NN + d * NHW + tid;
    unsafeAtomicAdd(&out[o],          a0);
    unsafeAtomicAdd(&out[o + NN],     a1);
    unsafeAtomicAdd(&out[o + 2 * NN], a2);
    unsafeAtomicAdd(&out[o + 3 * NN], a3);
}

extern "C" void kernel_launch(void* const* d_in, const int* in_sizes, int n_in,
                              void* d_out, int out_size, void* d_ws, size_t ws_size,
                              hipStream_t stream) {
    const float* x  = (const float*)d_in[0];
    const float* wk = (const float*)d_in[1];
    const float* bk = (const float*)d_in[2];
    const float* wq = (const float*)d_in[3];
    const float* bq = (const float*)d_in[4];
    const float* wv = (const float*)d_in[5];
    const float* bv = (const float*)d_in[6];
    const float* wa = (const float*)d_in[7];
    const float* ba = (const float*)d_in[8];
    float* out = (float*)d_out;

    float* ws   = (float*)d_ws;
    float* kbuf = ws;                        // [2][32][2048]   131072
    float* qbuf = kbuf + BB * CQ * NN;       // [2][32][2048]   131072
    float* vbuf = qbuf + BB * CQ * NN;       // [2][32][2048]   131072
    float* zbuf = vbuf + BB * CQ * NN;       // [32][2048]      65536
    float* ybuf = zbuf + CQ * NN;            // [32][2048][2]   131072
    float* mqb  = ybuf + BB * CQ * NN;       // [2][32]         64

    init_kernel<<<2304, 256, 0, stream>>>(bk, bq, bv, ba, x, kbuf, qbuf, vbuf, out, zbuf, ybuf);
    conv_qkv_kernel<<<1024, 256, 0, stream>>>(x, wk, wq, wv, kbuf, qbuf, vbuf);
    qmax_kernel<<<64, 256, 0, stream>>>(qbuf, mqb);
    mz_partial_kernel<<<1024, 256, 0, stream>>>(kbuf, qbuf, mqb, zbuf);
    att_partial_kernel<<<1024, 256, 0, stream>>>(kbuf, qbuf, vbuf, mqb, zbuf, ybuf);
    conv_out_kernel<<<1024, 256, 0, stream>>>(ybuf, wa, out);
}

// Round 13
// 103.158 us; speedup vs baseline: 1.2768x; 1.2768x over previous
//
#include <hip/hip_runtime.h>

#define BB 2
#define CIN 64
#define CQ 32
#define DD 8
#define HH 16
#define WWW 16
#define NN 2048   // D*H*W
#define NHW 256   // H*W
#define COUT 64

#define XPLANE 324          // 18*18 padded plane (conv_out)
#define CI_OUT 8            // ci per block (out conv) -- single stage

// conv_qkv spatial-quad geometry
#define QROWS 18
#define QCOLS 20
#define QPLANE (QROWS * QCOLS)   // 360 floats
#define QCI 4               // ci per staging phase

#define LOG2E 1.44269504088896340736f

__device__ __forceinline__ float fast_exp2(float x) {
#if __has_builtin(__builtin_amdgcn_exp2f)
    return __builtin_amdgcn_exp2f(x);    // single v_exp_f32
#else
    return exp2f(x);
#endif
}

// ---- init: qkv <- bias ; out <- x + bias ; zbuf,ybuf <- 0 ----
__global__ __launch_bounds__(256) void init_kernel(
    const float* __restrict__ bk, const float* __restrict__ bq, const float* __restrict__ bv,
    const float* __restrict__ ba, const float* __restrict__ x,
    float* __restrict__ kout, float* __restrict__ qout, float* __restrict__ vout,
    float* __restrict__ out, float* __restrict__ zbuf, float* __restrict__ ybuf)
{
    int i = blockIdx.x * 256 + threadIdx.x;
    if (i < BB * CQ * NN) {
        int co = (i >> 11) & 31;
        kout[i] = bk[co];
        qout[i] = bq[co];
        vout[i] = bv[co];
    } else if (i < 3 * BB * CQ * NN) {
        int j = i - BB * CQ * NN;             // 0 .. 262143
        int co = (j >> 11) & 63;
        out[j] = x[j] + ba[co];
    } else if (i < 3 * BB * CQ * NN + CQ * NN) {
        zbuf[i - 3 * BB * CQ * NN] = 0.f;
    } else {
        ybuf[i - 3 * BB * CQ * NN - CQ * NN] = 0.f;
    }
}

// ---- fused k,q,v conv: grid 512 = 8cisplit(HIGH) x {2b,2dq,16co2}(LOW) ----
// r10 structure (SGPR weights, w-quad, conflict-free h=lane&15 map) with
// TWO output channels per block: every per-ci overhead (s_load clusters,
// LDS window reads, staging, epilogue) is amortized over 2x the FMAs.
// r12's weight-via-LDS falsified the lgkm-drain theory (VALU 15%, LDS-bound);
// SGPR weights restored. Split partners differ only in bid>>6 -> same bid%8
// -> same XCD (r8 rule; 64 = 0 mod 8).
__global__ __launch_bounds__(256, 2) void conv_qkv_kernel(
    const float* __restrict__ x,
    const float* __restrict__ wk, const float* __restrict__ wq, const float* __restrict__ wv,
    float* __restrict__ kout, float* __restrict__ qout, float* __restrict__ vout)
{
    int bid   = blockIdx.x;
    int split = bid >> 6;          // 0..7 HIGH bits
    int inner = bid & 63;
    int co2   = inner & 15;
    int dq    = (inner >> 4) & 1;
    int b     = inner >> 5;
    int co0   = co2 << 1;          // output channels co0, co0+1
    int ci0   = split << 3;        // 8 ci per split
    int d0    = dq << 2;           // output planes d0 .. d0+3

    __shared__ float smem[QCI * 6 * QPLANE];   // 34560 B; epilogue reuses first 24 KB
    float* xl = smem;
    float* tl = smem;              // alias: xl dead before tl writes (barrier-separated)

    int tid = threadIdx.x;
    int hw = tid >> 4;
    int ww = tid & 15;
    int wr = (hw + 1) * QCOLS + (ww + 1);
    int pn  = tid >> 6;            // 0..3 d-plane (wave id)
    int rem = tid & 63;
    int h   = rem & 15;            // 0..15  (bank-conflict-free read map)
    int wqi = rem >> 4;            // 0..3

    const float* xb = x + ((size_t)b * CIN + ci0) * NN;

    float r[QCI * 6];
    #pragma unroll
    for (int p = 0; p < 6; ++p) {
        int dd = d0 - 1 + p;
        if (dd >= 0 && dd < DD) {              // block-uniform
            #pragma unroll
            for (int cl = 0; cl < QCI; ++cl)
                r[cl * 6 + p] = xb[(size_t)cl * NN + dd * NHW + tid];
        }
    }
    for (int i = tid; i < QCI * 6 * QPLANE; i += 256) xl[i] = 0.f;
    __syncthreads();
    #pragma unroll
    for (int p = 0; p < 6; ++p) {
        int dd = d0 - 1 + p;
        if (dd >= 0 && dd < DD) {
            #pragma unroll
            for (int cl = 0; cl < QCI; ++cl)
                xl[cl * 6 * QPLANE + p * QPLANE + wr] = r[cl * 6 + p];
        }
    }

    // acc sets: 0 = k@co0, 1 = k@co0+1, 2 = q@co0, 3 = q@co0+1, 4 = v@co0, 5 = v@co0+1
    float acc[6][4];
    #pragma unroll
    for (int s = 0; s < 6; ++s)
        #pragma unroll
        for (int o = 0; o < 4; ++o) acc[s][o] = 0.f;

    #pragma unroll 1
    for (int ph = 0; ph < 2; ++ph) {
        __syncthreads();
        if (ph == 0) {
            #pragma unroll
            for (int p = 0; p < 6; ++p) {
                int dd = d0 - 1 + p;
                if (dd >= 0 && dd < DD) {
                    #pragma unroll
                    for (int cl = 0; cl < QCI; ++cl)
                        r[cl * 6 + p] = xb[(size_t)(QCI + cl) * NN + dd * NHW + tid];
                }
            }
        }

        for (int cl = 0; cl < QCI; ++cl) {
            int ci = ci0 + ph * QCI + cl;
            const float* wk0 = wk + ((size_t)co0 * CIN + ci) * 27;
            const float* wk1 = wk0 + (size_t)CIN * 27;
            const float* wq0 = wq + ((size_t)co0 * CIN + ci) * 27;
            const float* wq1 = wq0 + (size_t)CIN * 27;
            const float* wv0 = wv + ((size_t)co0 * CIN + ci) * 27;
            const float* wv1 = wv0 + (size_t)CIN * 27;
            const float* xp  = xl + cl * 6 * QPLANE + pn * QPLANE + h * QCOLS + wqi * 4;

            #pragma unroll
            for (int kd = 0; kd < 3; ++kd) {
                // per-kd weight cluster: 54 wave-uniform words -> SGPRs
                float ws[6][9];
                #pragma unroll
                for (int j = 0; j < 9; ++j) {
                    int t = kd * 9 + j;
                    ws[0][j] = wk0[t]; ws[1][j] = wk1[t];
                    ws[2][j] = wq0[t]; ws[3][j] = wq1[t];
                    ws[4][j] = wv0[t]; ws[5][j] = wv1[t];
                }
                #pragma unroll
                for (int kh = 0; kh < 3; ++kh) {
                    const float* xr = xp + kd * QPLANE + kh * QCOLS;
                    float4 xa  = *(const float4*)xr;
                    float2 xb2 = *(const float2*)(xr + 4);
                    float xw[6] = {xa.x, xa.y, xa.z, xa.w, xb2.x, xb2.y};
                    #pragma unroll
                    for (int kw = 0; kw < 3; ++kw) {
                        int t = kh * 3 + kw;
                        #pragma unroll
                        for (int o = 0; o < 4; ++o) {
                            float xv = xw[o + kw];
                            acc[0][o] = fmaf(ws[0][t], xv, acc[0][o]);
                            acc[1][o] = fmaf(ws[1][t], xv, acc[1][o]);
                            acc[2][o] = fmaf(ws[2][t], xv, acc[2][o]);
                            acc[3][o] = fmaf(ws[3][t], xv, acc[3][o]);
                            acc[4][o] = fmaf(ws[4][t], xv, acc[4][o]);
                            acc[5][o] = fmaf(ws[5][t], xv, acc[5][o]);
                        }
                    }
                }
            }
        }

        __syncthreads();
        if (ph == 0) {
            #pragma unroll
            for (int p = 0; p < 6; ++p) {
                int dd = d0 - 1 + p;
                if (dd >= 0 && dd < DD) {
                    #pragma unroll
                    for (int cl = 0; cl < QCI; ++cl)
                        xl[cl * 6 * QPLANE + p * QPLANE + wr] = r[cl * 6 + p];
                }
            }
        }
    }

    // ---- epilogue: LDS transpose (aliased into xl) -> contiguous atomic lanes ----
    size_t base = ((size_t)b * CQ + co0) * NN + d0 * NHW;
    int wloc = pn * 256 + h * 16 + wqi * 4;
    __syncthreads();   // all xl reads complete before tl overwrite
    #pragma unroll
    for (int s = 0; s < 6; ++s) {
        float4 f; f.x = acc[s][0]; f.y = acc[s][1]; f.z = acc[s][2]; f.w = acc[s][3];
        *(float4*)&tl[s * 1024 + wloc] = f;
    }
    __syncthreads();
    #pragma unroll
    for (int p = 0; p < 4; ++p) {
        unsafeAtomicAdd(&kout[base + p * NHW + tid],      tl[0 * 1024 + p * 256 + tid]);
        unsafeAtomicAdd(&kout[base + NN + p * NHW + tid], tl[1 * 1024 + p * 256 + tid]);
        unsafeAtomicAdd(&qout[base + p * NHW + tid],      tl[2 * 1024 + p * 256 + tid]);
        unsafeAtomicAdd(&qout[base + NN + p * NHW + tid], tl[3 * 1024 + p * 256 + tid]);
        unsafeAtomicAdd(&vout[base + p * NHW + tid],      tl[4 * 1024 + p * 256 + tid]);
        unsafeAtomicAdd(&vout[base + NN + p * NHW + tid], tl[5 * 1024 + p * 256 + tid]);
    }
}

// ---- per-(b,c) row max|q|: grid 64 x 256 ----
__global__ __launch_bounds__(256) void qmax_kernel(
    const float* __restrict__ qbuf, float* __restrict__ mq)
{
    int row = blockIdx.x;
    int tid = threadIdx.x;
    const float4* q = (const float4*)(qbuf + (size_t)row * NN);
    float4 v0 = q[tid], v1 = q[tid + 256];
    float mx = fmaxf(fmaxf(fmaxf(fabsf(v0.x), fabsf(v0.y)), fmaxf(fabsf(v0.z), fabsf(v0.w))),
                     fmaxf(fmaxf(fabsf(v1.x), fabsf(v1.y)), fmaxf(fabsf(v1.z), fabsf(v1.w))));
    #pragma unroll
    for (int off = 32; off; off >>= 1)
        mx = fmaxf(mx, __shfl_down(mx, off, 64));
    __shared__ float red[4];
    if ((tid & 63) == 0) red[tid >> 6] = mx;
    __syncthreads();
    if (tid == 0) mq[row] = fmaxf(fmaxf(red[0], red[1]), fmaxf(red[2], red[3]));
}

// ---- softmax denominators with upper-bound shift: grid 1024 ----
__global__ __launch_bounds__(256) void mz_partial_kernel(
    const float* __restrict__ kbuf, const float* __restrict__ qbuf,
    const float* __restrict__ mq, float* __restrict__ zbuf)
{
    int bid = blockIdx.x;
    int nchunk = bid >> 7;
    int c      = (bid >> 2) & 31;
    int mtile  = bid & 3;

    __shared__ float q0l[256], q1l[256];
    int tid = threadIdx.x;
    int n0 = nchunk * 256;
    if (tid < 64) {
        float4 v = ((const float4*)(qbuf + (size_t)c * NN + n0))[tid];
        v.x *= LOG2E; v.y *= LOG2E; v.z *= LOG2E; v.w *= LOG2E;
        ((float4*)q0l)[tid] = v;
    } else if (tid < 128) {
        float4 v = ((const float4*)(qbuf + (size_t)(CQ + c) * NN + n0))[tid - 64];
        v.x *= LOG2E; v.y *= LOG2E; v.z *= LOG2E; v.w *= LOG2E;
        ((float4*)q1l)[tid - 64] = v;
    }
    __syncthreads();

    int m = mtile * 512 + tid * 2;
    float2 k0 = *(const float2*)(kbuf + (size_t)c * NN + m);
    float2 k1 = *(const float2*)(kbuf + (size_t)(CQ + c) * NN + m);
    float mq0 = mq[c], mq1 = mq[CQ + c];

    float nma = -LOG2E * fmaf(fabsf(k0.x), mq0, fabsf(k1.x) * mq1);
    float nmb = -LOG2E * fmaf(fabsf(k0.y), mq0, fabsf(k1.y) * mq1);

    const float4* q0v = (const float4*)q0l;
    const float4* q1v = (const float4*)q1l;

    float za = 0.f, zb = 0.f;
    #pragma unroll 4
    for (int i = 0; i < 64; ++i) {
        float4 a = q0v[i], b4 = q1v[i];
        za += fast_exp2(fmaf(k0.x, a.x, fmaf(k1.x, b4.x, nma)))
            + fast_exp2(fmaf(k0.x, a.y, fmaf(k1.x, b4.y, nma)))
            + fast_exp2(fmaf(k0.x, a.z, fmaf(k1.x, b4.z, nma)))
            + fast_exp2(fmaf(k0.x, a.w, fmaf(k1.x, b4.w, nma)));
        zb += fast_exp2(fmaf(k0.y, a.x, fmaf(k1.y, b4.x, nmb)))
            + fast_exp2(fmaf(k0.y, a.y, fmaf(k1.y, b4.y, nmb)))
            + fast_exp2(fmaf(k0.y, a.z, fmaf(k1.y, b4.z, nmb)))
            + fast_exp2(fmaf(k0.y, a.w, fmaf(k1.y, b4.w, nmb)));
    }
    unsafeAtomicAdd(&zbuf[(size_t)c * NN + m],     za);
    unsafeAtomicAdd(&zbuf[(size_t)c * NN + m + 1], zb);
}

// ---- attention apply, accumulating directly into ybuf: grid 1024 ----
__global__ __launch_bounds__(256) void att_partial_kernel(
    const float* __restrict__ kbuf, const float* __restrict__ qbuf,
    const float* __restrict__ vbuf,
    const float* __restrict__ mq, const float* __restrict__ zbuf,
    float* __restrict__ ybuf)
{
    int bid = blockIdx.x;
    int mchunk = bid >> 7;
    int c      = (bid >> 2) & 31;
    int ntile  = bid & 3;

    __shared__ float k0l[256], k1l[256], vz0l[256], vz1l[256], nMl[256];
    int tid = threadIdx.x;
    {
        int m = mchunk * 256 + tid;
        float k0 = kbuf[(size_t)c * NN + m];
        float k1 = kbuf[(size_t)(CQ + c) * NN + m];
        float mq0 = mq[c], mq1 = mq[CQ + c];
        float rz = 1.f / zbuf[(size_t)c * NN + m];
        k0l[tid]  = k0;
        k1l[tid]  = k1;
        vz0l[tid] = vbuf[(size_t)c * NN + m] * rz;
        vz1l[tid] = vbuf[(size_t)(CQ + c) * NN + m] * rz;
        nMl[tid]  = -LOG2E * fmaf(fabsf(k0), mq0, fabsf(k1) * mq1);
    }
    __syncthreads();

    int n = ntile * 512 + tid * 2;
    float2 q0 = *(const float2*)(qbuf + (size_t)c * NN + n);
    float2 q1 = *(const float2*)(qbuf + (size_t)(CQ + c) * NN + n);
    q0.x *= LOG2E; q0.y *= LOG2E;
    q1.x *= LOG2E; q1.y *= LOG2E;

    const float4* k0v = (const float4*)k0l;
    const float4* k1v = (const float4*)k1l;
    const float4* v0v = (const float4*)vz0l;
    const float4* v1v = (const float4*)vz1l;
    const float4* nMv = (const float4*)nMl;

    float a00 = 0.f, a01 = 0.f;   // b=0: n, n+1
    float a10 = 0.f, a11 = 0.f;   // b=1

    #pragma unroll 2
    for (int i = 0; i < 64; ++i) {
        float4 kk0 = k0v[i], kk1 = k1v[i], w0 = v0v[i], w1 = v1v[i], nm = nMv[i];
        #define ATTS(KX,K1X,W0X,W1X,NMX) { \
            float e0 = fast_exp2(fmaf(q0.x, KX, fmaf(q1.x, K1X, NMX))); \
            float e1 = fast_exp2(fmaf(q0.y, KX, fmaf(q1.y, K1X, NMX))); \
            a00 = fmaf(e0, W0X, a00); a10 = fmaf(e0, W1X, a10); \
            a01 = fmaf(e1, W0X, a01); a11 = fmaf(e1, W1X, a11); }
        ATTS(kk0.x, kk1.x, w0.x, w1.x, nm.x)
        ATTS(kk0.y, kk1.y, w0.y, w1.y, nm.y)
        ATTS(kk0.z, kk1.z, w0.z, w1.z, nm.z)
        ATTS(kk0.w, kk1.w, w0.w, w1.w, nm.w)
        #undef ATTS
    }

    size_t base = ((size_t)c * NN + n) * BB;   // ybuf flat [c][n][b]
    unsafeAtomicAdd(&ybuf[base + 0], a00);
    unsafeAtomicAdd(&ybuf[base + 1], a10);
    unsafeAtomicAdd(&ybuf[base + 2], a01);
    unsafeAtomicAdd(&ybuf[base + 3], a11);
}

// ---- final conv (32->64): grid 2b*8d*16cog*4cisplit = 1024 blocks ----
__global__ __launch_bounds__(256, 4) void conv_out_kernel(
    const float* __restrict__ ybuf,
    const float* __restrict__ wa,
    float* __restrict__ out)
{
    int bid   = blockIdx.x;
    int split = bid & 3;
    int cog   = (bid >> 2) & 15;
    int d     = (bid >> 6) & 7;
    int b     = bid >> 9;
    int co0   = cog << 2;
    int ci0   = split << 3;   // 8 ci per split

    __shared__ float yl[CI_OUT * 3 * XPLANE];   // 31104 B

    int tid = threadIdx.x;
    int h  = tid >> 4;
    int w  = tid & 15;
    int wr = (h + 1) * 18 + (w + 1);
    int rb = h * 18 + w;

    const float* yb = ybuf + ((size_t)b * CQ + ci0) * NN;   // [C,N,B] flat as [B][32][2048]

    float r[CI_OUT * 3];
    #pragma unroll
    for (int kd = 0; kd < 3; ++kd) {
        int dd = d + kd - 1;
        bool ok = (dd >= 0) && (dd < DD);
        #pragma unroll
        for (int cc = 0; cc < CI_OUT; ++cc)
            r[cc * 3 + kd] = ok ? yb[(size_t)cc * NN + dd * NHW + tid] : 0.f;
    }
    for (int i = tid; i < CI_OUT * 3 * XPLANE; i += 256) yl[i] = 0.f;
    __syncthreads();
    #pragma unroll
    for (int j = 0; j < CI_OUT * 3; ++j)
        yl[j * XPLANE + wr] = r[j];
    __syncthreads();

    float a0 = 0.f, a1 = 0.f, a2 = 0.f, a3 = 0.f;

    for (int cc = 0; cc < CI_OUT; ++cc) {
        int ci = ci0 + cc;
        const float* w0 = wa + ((size_t)(co0 + 0) * CQ + ci) * 27;
        const float* w1 = wa + ((size_t)(co0 + 1) * CQ + ci) * 27;
        const float* w2 = wa + ((size_t)(co0 + 2) * CQ + ci) * 27;
        const float* w3 = wa + ((size_t)(co0 + 3) * CQ + ci) * 27;
        const float* yp = yl + cc * 3 * XPLANE + rb;
        #pragma unroll
        for (int kd = 0; kd < 3; ++kd) {
            int dd = d + kd - 1;
            if (dd < 0 || dd >= DD) continue;   // block-uniform
            #pragma unroll
            for (int kh = 0; kh < 3; ++kh) {
                #pragma unroll
                for (int kw = 0; kw < 3; ++kw) {
                    float yv = yp[kd * XPLANE + kh * 18 + kw];
                    int t = kd * 9 + kh * 3 + kw;
                    a0 = fmaf(yv, w0[t], a0);
                    a1 = fmaf(yv, w1[t], a1);
                    a2 = fmaf(yv, w2[t], a2);
                    a3 = fmaf(yv, w3[t], a3);
                }
            }
        }
    }

    size_t o = ((size_t)b * COUT + co0) * NN + d * NHW + tid;
    unsafeAtomicAdd(&out[o],          a0);
    unsafeAtomicAdd(&out[o + NN],     a1);
    unsafeAtomicAdd(&out[o + 2 * NN], a2);
    unsafeAtomicAdd(&out[o + 3 * NN], a3);
}

extern "C" void kernel_launch(void* const* d_in, const int* in_sizes, int n_in,
                              void* d_out, int out_size, void* d_ws, size_t ws_size,
                              hipStream_t stream) {
    const float* x  = (const float*)d_in[0];
    const float* wk = (const float*)d_in[1];
    const float* bk = (const float*)d_in[2];
    const float* wq = (const float*)d_in[3];
    const float* bq = (const float*)d_in[4];
    const float* wv = (const float*)d_in[5];
    const float* bv = (const float*)d_in[6];
    const float* wa = (const float*)d_in[7];
    const float* ba = (const float*)d_in[8];
    float* out = (float*)d_out;

    float* ws   = (float*)d_ws;
    float* kbuf = ws;                        // [2][32][2048]   131072
    float* qbuf = kbuf + BB * CQ * NN;       // [2][32][2048]   131072
    float* vbuf = qbuf + BB * CQ * NN;       // [2][32][2048]   131072
    float* zbuf = vbuf + BB * CQ * NN;       // [32][2048]      65536
    float* ybuf = zbuf + CQ * NN;            // [32][2048][2]   131072
    float* mqb  = ybuf + BB * CQ * NN;       // [2][32]         64

    init_kernel<<<2304, 256, 0, stream>>>(bk, bq, bv, ba, x, kbuf, qbuf, vbuf, out, zbuf, ybuf);
    conv_qkv_kernel<<<512, 256, 0, stream>>>(x, wk, wq, wv, kbuf, qbuf, vbuf);
    qmax_kernel<<<64, 256, 0, stream>>>(qbuf, mqb);
    mz_partial_kernel<<<1024, 256, 0, stream>>>(kbuf, qbuf, mqb, zbuf);
    att_partial_kernel<<<1024, 256, 0, stream>>>(kbuf, qbuf, vbuf, mqb, zbuf, ybuf);
    conv_out_kernel<<<1024, 256, 0, stream>>>(ybuf, wa, out);
}

// Round 14
// 90.892 us; speedup vs baseline: 1.4491x; 1.1349x over previous
//
#include <hip/hip_runtime.h>

#define BB 2
#define CIN 64
#define CQ 32
#define DD 8
#define HH 16
#define WWW 16
#define NN 2048   // D*H*W
#define NHW 256   // H*W
#define COUT 64

#define XPLANE 324          // 18*18 padded plane (conv_out)
#define CI_OUT 8            // ci per block (out conv) -- single stage

// conv_qkv spatial-quad geometry
#define QROWS 18
#define QCOLS 20
#define QPLANE (QROWS * QCOLS)   // 360 floats
#define QCI 4               // ci per staging phase

#define LOG2E 1.44269504088896340736f

__device__ __forceinline__ float fast_exp2(float x) {
#if __has_builtin(__builtin_amdgcn_exp2f)
    return __builtin_amdgcn_exp2f(x);    // single v_exp_f32
#else
    return exp2f(x);
#endif
}

// ---- init: qkv <- bias ; out <- x + bias ; zbuf,ybuf <- 0 ----
__global__ __launch_bounds__(256) void init_kernel(
    const float* __restrict__ bk, const float* __restrict__ bq, const float* __restrict__ bv,
    const float* __restrict__ ba, const float* __restrict__ x,
    float* __restrict__ kout, float* __restrict__ qout, float* __restrict__ vout,
    float* __restrict__ out, float* __restrict__ zbuf, float* __restrict__ ybuf)
{
    int i = blockIdx.x * 256 + threadIdx.x;
    if (i < BB * CQ * NN) {
        int co = (i >> 11) & 31;
        kout[i] = bk[co];
        qout[i] = bq[co];
        vout[i] = bv[co];
    } else if (i < 3 * BB * CQ * NN) {
        int j = i - BB * CQ * NN;             // 0 .. 262143
        int co = (j >> 11) & 63;
        out[j] = x[j] + ba[co];
    } else if (i < 3 * BB * CQ * NN + CQ * NN) {
        zbuf[i - 3 * BB * CQ * NN] = 0.f;
    } else {
        ybuf[i - 3 * BB * CQ * NN - CQ * NN] = 0.f;
    }
}

// ---- fused k,q,v conv: grid 512 = 4cisplit(HIGH) x {2b,2dq,32co}(LOW) ----
// r10 structure restored exactly (proven 39.8us / 90.3 total), with ONE change:
// 1-deep software pipeline of window loads. Windows linearized w=0..8 over
// (kd,kh); window w+1 is fetched into the ping-pong buffer xw[2][6] BEFORE the
// 36-FMA burst of window w, so ds_read latency (~120cy) hides under FMAs
// (72cy/burst). Weight path unchanged: ws[3][9] 27-word SGPR clusters
// (r12/r13 showed 54+ word clusters overflow SGPR and balloon VALU issue).
__global__ __launch_bounds__(256, 2) void conv_qkv_kernel(
    const float* __restrict__ x,
    const float* __restrict__ wk, const float* __restrict__ wq, const float* __restrict__ wv,
    float* __restrict__ kout, float* __restrict__ qout, float* __restrict__ vout)
{
    int bid   = blockIdx.x;
    int split = bid >> 7;          // HIGH bits: split partners share bid%8 -> same XCD
    int inner = bid & 127;
    int co    = inner & 31;
    int dq    = (inner >> 5) & 1;
    int b     = inner >> 6;
    int ci0   = split << 4;        // 16 ci per split
    int d0    = dq << 2;           // output planes d0 .. d0+3

    __shared__ float xl[QCI * 6 * QPLANE];   // 34560 B
    __shared__ float tl[3 * 1024];           // 12 KB epilogue transpose buffer

    int tid = threadIdx.x;
    int hw = tid >> 4;
    int ww = tid & 15;
    int wr = (hw + 1) * QCOLS + (ww + 1);
    int pn  = tid >> 6;            // 0..3 d-plane (wave id)
    int rem = tid & 63;
    int h   = rem & 15;            // 0..15  (bank-conflict-free read map)
    int wqi = rem >> 4;            // 0..3

    const float* xb = x + ((size_t)b * CIN + ci0) * NN;

    float r[QCI * 6];
    #pragma unroll
    for (int p = 0; p < 6; ++p) {
        int dd = d0 - 1 + p;
        if (dd >= 0 && dd < DD) {              // block-uniform
            #pragma unroll
            for (int cl = 0; cl < QCI; ++cl)
                r[cl * 6 + p] = xb[(size_t)cl * NN + dd * NHW + tid];
        }
    }
    for (int i = tid; i < QCI * 6 * QPLANE; i += 256) xl[i] = 0.f;
    __syncthreads();
    #pragma unroll
    for (int p = 0; p < 6; ++p) {
        int dd = d0 - 1 + p;
        if (dd >= 0 && dd < DD) {
            #pragma unroll
            for (int cl = 0; cl < QCI; ++cl)
                xl[cl * 6 * QPLANE + p * QPLANE + wr] = r[cl * 6 + p];
        }
    }

    float acc[3][4];
    #pragma unroll
    for (int s = 0; s < 3; ++s)
        #pragma unroll
        for (int o = 0; o < 4; ++o) acc[s][o] = 0.f;

    #pragma unroll 1
    for (int ph = 0; ph < 4; ++ph) {
        __syncthreads();
        if (ph < 3) {
            #pragma unroll
            for (int p = 0; p < 6; ++p) {
                int dd = d0 - 1 + p;
                if (dd >= 0 && dd < DD) {
                    #pragma unroll
                    for (int cl = 0; cl < QCI; ++cl)
                        r[cl * 6 + p] = xb[(size_t)((ph + 1) * QCI + cl) * NN + dd * NHW + tid];
                }
            }
        }

        for (int cl = 0; cl < QCI; ++cl) {
            int ci = ci0 + ph * QCI + cl;
            const float* wk0 = wk + ((size_t)co * CIN + ci) * 27;
            const float* wq0 = wq + ((size_t)co * CIN + ci) * 27;
            const float* wv0 = wv + ((size_t)co * CIN + ci) * 27;
            const float* xp  = xl + cl * 6 * QPLANE + pn * QPLANE + h * QCOLS + wqi * 4;

            // ---- 1-deep pipelined window stream: w = kd*3 + kh ----
            float xw[2][6];
            {   // preload window 0 (kd=0,kh=0)
                float4 xa  = *(const float4*)xp;
                float2 xb2 = *(const float2*)(xp + 4);
                xw[0][0] = xa.x; xw[0][1] = xa.y; xw[0][2] = xa.z;
                xw[0][3] = xa.w; xw[0][4] = xb2.x; xw[0][5] = xb2.y;
            }
            float ws[3][9];
            #pragma unroll
            for (int w = 0; w < 9; ++w) {
                const int kd = w / 3;
                const int kh = w - kd * 3;
                if (kh == 0) {
                    // per-kd weight cluster: 27 wave-uniform words -> SGPRs
                    #pragma unroll
                    for (int j = 0; j < 9; ++j) {
                        int t = kd * 9 + j;
                        ws[0][j] = wk0[t]; ws[1][j] = wq0[t]; ws[2][j] = wv0[t];
                    }
                }
                if (w < 8) {
                    // prefetch window w+1 while window w's FMAs run
                    const int w2  = w + 1;
                    const int kd2 = w2 / 3;
                    const int kh2 = w2 - kd2 * 3;
                    const float* xr = xp + kd2 * QPLANE + kh2 * QCOLS;
                    float4 xa  = *(const float4*)xr;
                    float2 xb2 = *(const float2*)(xr + 4);
                    const int nb = w2 & 1;
                    xw[nb][0] = xa.x; xw[nb][1] = xa.y; xw[nb][2] = xa.z;
                    xw[nb][3] = xa.w; xw[nb][4] = xb2.x; xw[nb][5] = xb2.y;
                }
                const int cb = w & 1;
                #pragma unroll
                for (int kw = 0; kw < 3; ++kw) {
                    int t = kh * 3 + kw;
                    #pragma unroll
                    for (int o = 0; o < 4; ++o) {
                        float xv = xw[cb][o + kw];
                        acc[0][o] = fmaf(ws[0][t], xv, acc[0][o]);
                        acc[1][o] = fmaf(ws[1][t], xv, acc[1][o]);
                        acc[2][o] = fmaf(ws[2][t], xv, acc[2][o]);
                    }
                }
            }
        }

        __syncthreads();
        if (ph < 3) {
            #pragma unroll
            for (int p = 0; p < 6; ++p) {
                int dd = d0 - 1 + p;
                if (dd >= 0 && dd < DD) {
                    #pragma unroll
                    for (int cl = 0; cl < QCI; ++cl)
                        xl[cl * 6 * QPLANE + p * QPLANE + wr] = r[cl * 6 + p];
                }
            }
        }
    }

    // ---- epilogue: LDS transpose -> contiguous atomic lanes ----
    size_t base = ((size_t)b * CQ + co) * NN + d0 * NHW;
    int wloc = pn * 256 + h * 16 + wqi * 4;
    __syncthreads();
    {
        float4 f0; f0.x = acc[0][0]; f0.y = acc[0][1]; f0.z = acc[0][2]; f0.w = acc[0][3];
        float4 f1; f1.x = acc[1][0]; f1.y = acc[1][1]; f1.z = acc[1][2]; f1.w = acc[1][3];
        float4 f2; f2.x = acc[2][0]; f2.y = acc[2][1]; f2.z = acc[2][2]; f2.w = acc[2][3];
        *(float4*)&tl[wloc]        = f0;
        *(float4*)&tl[1024 + wloc] = f1;
        *(float4*)&tl[2048 + wloc] = f2;
    }
    __syncthreads();
    #pragma unroll
    for (int p = 0; p < 4; ++p) {
        unsafeAtomicAdd(&kout[base + p * NHW + tid], tl[p * 256 + tid]);
        unsafeAtomicAdd(&qout[base + p * NHW + tid], tl[1024 + p * 256 + tid]);
        unsafeAtomicAdd(&vout[base + p * NHW + tid], tl[2048 + p * 256 + tid]);
    }
}

// ---- per-(b,c) row max|q|: grid 64 x 256 ----
__global__ __launch_bounds__(256) void qmax_kernel(
    const float* __restrict__ qbuf, float* __restrict__ mq)
{
    int row = blockIdx.x;
    int tid = threadIdx.x;
    const float4* q = (const float4*)(qbuf + (size_t)row * NN);
    float4 v0 = q[tid], v1 = q[tid + 256];
    float mx = fmaxf(fmaxf(fmaxf(fabsf(v0.x), fabsf(v0.y)), fmaxf(fabsf(v0.z), fabsf(v0.w))),
                     fmaxf(fmaxf(fabsf(v1.x), fabsf(v1.y)), fmaxf(fabsf(v1.z), fabsf(v1.w))));
    #pragma unroll
    for (int off = 32; off; off >>= 1)
        mx = fmaxf(mx, __shfl_down(mx, off, 64));
    __shared__ float red[4];
    if ((tid & 63) == 0) red[tid >> 6] = mx;
    __syncthreads();
    if (tid == 0) mq[row] = fmaxf(fmaxf(red[0], red[1]), fmaxf(red[2], red[3]));
}

// ---- softmax denominators with upper-bound shift: grid 1024 ----
__global__ __launch_bounds__(256) void mz_partial_kernel(
    const float* __restrict__ kbuf, const float* __restrict__ qbuf,
    const float* __restrict__ mq, float* __restrict__ zbuf)
{
    int bid = blockIdx.x;
    int nchunk = bid >> 7;
    int c      = (bid >> 2) & 31;
    int mtile  = bid & 3;

    __shared__ float q0l[256], q1l[256];
    int tid = threadIdx.x;
    int n0 = nchunk * 256;
    if (tid < 64) {
        float4 v = ((const float4*)(qbuf + (size_t)c * NN + n0))[tid];
        v.x *= LOG2E; v.y *= LOG2E; v.z *= LOG2E; v.w *= LOG2E;
        ((float4*)q0l)[tid] = v;
    } else if (tid < 128) {
        float4 v = ((const float4*)(qbuf + (size_t)(CQ + c) * NN + n0))[tid - 64];
        v.x *= LOG2E; v.y *= LOG2E; v.z *= LOG2E; v.w *= LOG2E;
        ((float4*)q1l)[tid - 64] = v;
    }
    __syncthreads();

    int m = mtile * 512 + tid * 2;
    float2 k0 = *(const float2*)(kbuf + (size_t)c * NN + m);
    float2 k1 = *(const float2*)(kbuf + (size_t)(CQ + c) * NN + m);
    float mq0 = mq[c], mq1 = mq[CQ + c];

    float nma = -LOG2E * fmaf(fabsf(k0.x), mq0, fabsf(k1.x) * mq1);
    float nmb = -LOG2E * fmaf(fabsf(k0.y), mq0, fabsf(k1.y) * mq1);

    const float4* q0v = (const float4*)q0l;
    const float4* q1v = (const float4*)q1l;

    float za = 0.f, zb = 0.f;
    #pragma unroll 4
    for (int i = 0; i < 64; ++i) {
        float4 a = q0v[i], b4 = q1v[i];
        za += fast_exp2(fmaf(k0.x, a.x, fmaf(k1.x, b4.x, nma)))
            + fast_exp2(fmaf(k0.x, a.y, fmaf(k1.x, b4.y, nma)))
            + fast_exp2(fmaf(k0.x, a.z, fmaf(k1.x, b4.z, nma)))
            + fast_exp2(fmaf(k0.x, a.w, fmaf(k1.x, b4.w, nma)));
        zb += fast_exp2(fmaf(k0.y, a.x, fmaf(k1.y, b4.x, nmb)))
            + fast_exp2(fmaf(k0.y, a.y, fmaf(k1.y, b4.y, nmb)))
            + fast_exp2(fmaf(k0.y, a.z, fmaf(k1.y, b4.z, nmb)))
            + fast_exp2(fmaf(k0.y, a.w, fmaf(k1.y, b4.w, nmb)));
    }
    unsafeAtomicAdd(&zbuf[(size_t)c * NN + m],     za);
    unsafeAtomicAdd(&zbuf[(size_t)c * NN + m + 1], zb);
}

// ---- attention apply, accumulating directly into ybuf: grid 1024 ----
__global__ __launch_bounds__(256) void att_partial_kernel(
    const float* __restrict__ kbuf, const float* __restrict__ qbuf,
    const float* __restrict__ vbuf,
    const float* __restrict__ mq, const float* __restrict__ zbuf,
    float* __restrict__ ybuf)
{
    int bid = blockIdx.x;
    int mchunk = bid >> 7;
    int c      = (bid >> 2) & 31;
    int ntile  = bid & 3;

    __shared__ float k0l[256], k1l[256], vz0l[256], vz1l[256], nMl[256];
    int tid = threadIdx.x;
    {
        int m = mchunk * 256 + tid;
        float k0 = kbuf[(size_t)c * NN + m];
        float k1 = kbuf[(size_t)(CQ + c) * NN + m];
        float mq0 = mq[c], mq1 = mq[CQ + c];
        float rz = 1.f / zbuf[(size_t)c * NN + m];
        k0l[tid]  = k0;
        k1l[tid]  = k1;
        vz0l[tid] = vbuf[(size_t)c * NN + m] * rz;
        vz1l[tid] = vbuf[(size_t)(CQ + c) * NN + m] * rz;
        nMl[tid]  = -LOG2E * fmaf(fabsf(k0), mq0, fabsf(k1) * mq1);
    }
    __syncthreads();

    int n = ntile * 512 + tid * 2;
    float2 q0 = *(const float2*)(qbuf + (size_t)c * NN + n);
    float2 q1 = *(const float2*)(qbuf + (size_t)(CQ + c) * NN + n);
    q0.x *= LOG2E; q0.y *= LOG2E;
    q1.x *= LOG2E; q1.y *= LOG2E;

    const float4* k0v = (const float4*)k0l;
    const float4* k1v = (const float4*)k1l;
    const float4* v0v = (const float4*)vz0l;
    const float4* v1v = (const float4*)vz1l;
    const float4* nMv = (const float4*)nMl;

    float a00 = 0.f, a01 = 0.f;   // b=0: n, n+1
    float a10 = 0.f, a11 = 0.f;   // b=1

    #pragma unroll 2
    for (int i = 0; i < 64; ++i) {
        float4 kk0 = k0v[i], kk1 = k1v[i], w0 = v0v[i], w1 = v1v[i], nm = nMv[i];
        #define ATTS(KX,K1X,W0X,W1X,NMX) { \
            float e0 = fast_exp2(fmaf(q0.x, KX, fmaf(q1.x, K1X, NMX))); \
            float e1 = fast_exp2(fmaf(q0.y, KX, fmaf(q1.y, K1X, NMX))); \
            a00 = fmaf(e0, W0X, a00); a10 = fmaf(e0, W1X, a10); \
            a01 = fmaf(e1, W0X, a01); a11 = fmaf(e1, W1X, a11); }
        ATTS(kk0.x, kk1.x, w0.x, w1.x, nm.x)
        ATTS(kk0.y, kk1.y, w0.y, w1.y, nm.y)
        ATTS(kk0.z, kk1.z, w0.z, w1.z, nm.z)
        ATTS(kk0.w, kk1.w, w0.w, w1.w, nm.w)
        #undef ATTS
    }

    size_t base = ((size_t)c * NN + n) * BB;   // ybuf flat [c][n][b]
    unsafeAtomicAdd(&ybuf[base + 0], a00);
    unsafeAtomicAdd(&ybuf[base + 1], a10);
    unsafeAtomicAdd(&ybuf[base + 2], a01);
    unsafeAtomicAdd(&ybuf[base + 3], a11);
}

// ---- final conv (32->64): grid 2b*8d*16cog*4cisplit = 1024 blocks ----
__global__ __launch_bounds__(256, 4) void conv_out_kernel(
    const float* __restrict__ ybuf,
    const float* __restrict__ wa,
    float* __restrict__ out)
{
    int bid   = blockIdx.x;
    int split = bid & 3;
    int cog   = (bid >> 2) & 15;
    int d     = (bid >> 6) & 7;
    int b     = bid >> 9;
    int co0   = cog << 2;
    int ci0   = split << 3;   // 8 ci per split

    __shared__ float yl[CI_OUT * 3 * XPLANE];   // 31104 B

    int tid = threadIdx.x;
    int h  = tid >> 4;
    int w  = tid & 15;
    int wr = (h + 1) * 18 + (w + 1);
    int rb = h * 18 + w;

    const float* yb = ybuf + ((size_t)b * CQ + ci0) * NN;   // [C,N,B] flat as [B][32][2048]

    float r[CI_OUT * 3];
    #pragma unroll
    for (int kd = 0; kd < 3; ++kd) {
        int dd = d + kd - 1;
        bool ok = (dd >= 0) && (dd < DD);
        #pragma unroll
        for (int cc = 0; cc < CI_OUT; ++cc)
            r[cc * 3 + kd] = ok ? yb[(size_t)cc * NN + dd * NHW + tid] : 0.f;
    }
    for (int i = tid; i < CI_OUT * 3 * XPLANE; i += 256) yl[i] = 0.f;
    __syncthreads();
    #pragma unroll
    for (int j = 0; j < CI_OUT * 3; ++j)
        yl[j * XPLANE + wr] = r[j];
    __syncthreads();

    float a0 = 0.f, a1 = 0.f, a2 = 0.f, a3 = 0.f;

    for (int cc = 0; cc < CI_OUT; ++cc) {
        int ci = ci0 + cc;
        const float* w0 = wa + ((size_t)(co0 + 0) * CQ + ci) * 27;
        const float* w1 = wa + ((size_t)(co0 + 1) * CQ + ci) * 27;
        const float* w2 = wa + ((size_t)(co0 + 2) * CQ + ci) * 27;
        const float* w3 = wa + ((size_t)(co0 + 3) * CQ + ci) * 27;
        const float* yp = yl + cc * 3 * XPLANE + rb;
        #pragma unroll
        for (int kd = 0; kd < 3; ++kd) {
            int dd = d + kd - 1;
            if (dd < 0 || dd >= DD) continue;   // block-uniform
            #pragma unroll
            for (int kh = 0; kh < 3; ++kh) {
                #pragma unroll
                for (int kw = 0; kw < 3; ++kw) {
                    float yv = yp[kd * XPLANE + kh * 18 + kw];
                    int t = kd * 9 + kh * 3 + kw;
                    a0 = fmaf(yv, w0[t], a0);
                    a1 = fmaf(yv, w1[t], a1);
                    a2 = fmaf(yv, w2[t], a2);
                    a3 = fmaf(yv, w3[t], a3);
                }
            }
        }
    }

    size_t o = ((size_t)b * COUT + co0) * NN + d * NHW + tid;
    unsafeAtomicAdd(&out[o],          a0);
    unsafeAtomicAdd(&out[o + NN],     a1);
    unsafeAtomicAdd(&out[o + 2 * NN], a2);
    unsafeAtomicAdd(&out[o + 3 * NN], a3);
}

extern "C" void kernel_launch(void* const* d_in, const int* in_sizes, int n_in,
                              void* d_out, int out_size, void* d_ws, size_t ws_size,
                              hipStream_t stream) {
    const float* x  = (const float*)d_in[0];
    const float* wk = (const float*)d_in[1];
    const float* bk = (const float*)d_in[2];
    const float* wq = (const float*)d_in[3];
    const float* bq = (const float*)d_in[4];
    const float* wv = (const float*)d_in[5];
    const float* bv = (const float*)d_in[6];
    const float* wa = (const float*)d_in[7];
    const float* ba = (const float*)d_in[8];
    float* out = (float*)d_out;

    float* ws   = (float*)d_ws;
    float* kbuf = ws;                        // [2][32][2048]   131072
    float* qbuf = kbuf + BB * CQ * NN;       // [2][32][2048]   131072
    float* vbuf = qbuf + BB * CQ * NN;       // [2][32][2048]   131072
    float* zbuf = vbuf + BB * CQ * NN;       // [32][2048]      65536
    float* ybuf = zbuf + CQ * NN;            // [32][2048][2]   131072
    float* mqb  = ybuf + BB * CQ * NN;       // [2][32]         64

    init_kernel<<<2304, 256, 0, stream>>>(bk, bq, bv, ba, x, kbuf, qbuf, vbuf, out, zbuf, ybuf);
    conv_qkv_kernel<<<512, 256, 0, stream>>>(x, wk, wq, wv, kbuf, qbuf, vbuf);
    qmax_kernel<<<64, 256, 0, stream>>>(qbuf, mqb);
    mz_partial_kernel<<<1024, 256, 0, stream>>>(kbuf, qbuf, mqb, zbuf);
    att_partial_kernel<<<1024, 256, 0, stream>>>(kbuf, qbuf, vbuf, mqb, zbuf, ybuf);
    conv_out_kernel<<<1024, 256, 0, stream>>>(ybuf, wa, out);
}